// Round 2
// baseline (332.063 us; speedup 1.0000x reference)
//
#include <hip/hip_runtime.h>
#include <hip/hip_fp16.h>

typedef __attribute__((ext_vector_type(8))) _Float16 f16x8;
typedef __attribute__((ext_vector_type(4))) _Float16 f16x4;
typedef __attribute__((ext_vector_type(4))) float    f32x4;

#define MFMA_F16(a,b,c) __builtin_amdgcn_mfma_f32_16x16x32_f16((a),(b),(c),0,0,0)

// ---------------- workspace layout (bytes) ----------------
// DEC16   @ 0        8 MB   [4096][1024] f16
// ENC16   @ 8 MB     8 MB
// WT      @ 16 MB    4x2 MB  wqT,wkT,wvT,woT  [n][k] f16
// QH      @ 24 MB    8 MB   [2][16][2048][64] f16
// KH      @ 32 MB    8 MB   [2][16][2048][64] f16
// VT      @ 40 MB    8 MB   [2][16][64][2048] f16
// CTX     @ 48 MB    8 MB   [4096][1024] f16
// total 56 MB

// ---------------- cast activations fp32 -> fp16 ----------------
__global__ __launch_bounds__(256) void k_cast(const float* __restrict__ dec, const float* __restrict__ enc,
                                              _Float16* __restrict__ dd, _Float16* __restrict__ de)
{
  int i = blockIdx.x * 256 + threadIdx.x;          // 1048576 threads * float4 = 4194304 elems
  float4 a = ((const float4*)dec)[i];
  float4 b = ((const float4*)enc)[i];
  f16x4 ha = {(_Float16)a.x, (_Float16)a.y, (_Float16)a.z, (_Float16)a.w};
  f16x4 hb = {(_Float16)b.x, (_Float16)b.y, (_Float16)b.z, (_Float16)b.w};
  ((f16x4*)dd)[i] = ha;
  ((f16x4*)de)[i] = hb;
}

// ---------------- transpose+cast weights: wT[n][k] = (f16)w[k][n] ----------------
__global__ __launch_bounds__(256) void k_wt(const float* __restrict__ wq, const float* __restrict__ wk,
                                            const float* __restrict__ wv, const float* __restrict__ wo,
                                            _Float16* __restrict__ dst0)
{
  __shared__ float tile[32][33];
  int z = blockIdx.z;
  const float* w = (z==0)?wq:(z==1)?wk:(z==2)?wv:wo;
  _Float16* dst = dst0 + (size_t)z * (1024u*1024u);
  int tx = threadIdx.x, ty = threadIdx.y;          // block (32,8)
  int n0 = blockIdx.x*32, k0 = blockIdx.y*32;
#pragma unroll
  for (int r = 0; r < 4; ++r)
    tile[ty + 8*r][tx] = w[(size_t)(k0 + ty + 8*r)*1024 + n0 + tx];
  __syncthreads();
#pragma unroll
  for (int r = 0; r < 4; ++r)
    dst[(size_t)(n0 + ty + 8*r)*1024 + k0 + tx] = (_Float16)tile[tx][ty + 8*r];
}

// ---------------- shared 128x128x1024 GEMM core (B^T form, f16, reg-staged dbuf LDS) ----------------
// A: [M][1024] f16 row-major; BT: [1024][1024] f16 (row n = column n of W).
// acc[i][j] is the wave's 4x4 grid of 16x16 C tiles; C layout: col=lane&15, row=4*(lane>>4)+reg.
__device__ __forceinline__ void gemm_core_128(const _Float16* __restrict__ A, const _Float16* __restrict__ BT,
                                              int m0, int n0, _Float16* lds, f32x4 acc[4][4])
{
  const int t    = threadIdx.x;
  const int lane = t & 63, wid = t >> 6;
  const int lr   = lane & 15, lg = lane >> 4;
  const int wm   = (wid & 1) * 64, wn = (wid >> 1) * 64;
  const int swz  = (lr >> 2) & 3;

  // staging: thread t owns 16B chunks c=t and c=t+256 of each tile (chunk c -> row c>>2, slot c&3).
  // slot holds logical k-chunk (slot ^ ((row>>2)&3))  [XOR swizzle -> 2-way-free ds_read_b128 later]
  const int cm0 = t >> 2,        ck0 = (((t      ) & 3) ^ (((t      ) >> 4) & 3)) * 8;
  const int cm1 = (t + 256) >> 2, ck1 = (((t + 256) & 3) ^ (((t + 256) >> 4) & 3)) * 8;
  const _Float16* Arow0 = A  + (size_t)(m0 + cm0) * 1024 + ck0;
  const _Float16* Arow1 = A  + (size_t)(m0 + cm1) * 1024 + ck1;
  const _Float16* Brow0 = BT + (size_t)(n0 + cm0) * 1024 + ck0;
  const _Float16* Brow1 = BT + (size_t)(n0 + cm1) * 1024 + ck1;

  int aoff[4], boff[4];
#pragma unroll
  for (int s = 0; s < 4; ++s) {
    aoff[s] = (wm + s*16 + lr)*32 + ((lg ^ swz) << 3);
    boff[s] = (wn + s*16 + lr)*32 + ((lg ^ swz) << 3);
  }

  const f32x4 z4 = {0.f,0.f,0.f,0.f};
#pragma unroll
  for (int i = 0; i < 4; ++i)
#pragma unroll
    for (int j = 0; j < 4; ++j) acc[i][j] = z4;

  { // prologue: stage k-tile 0 into buf 0
    uint4 a0 = *(const uint4*)Arow0;
    uint4 a1 = *(const uint4*)Arow1;
    uint4 b0 = *(const uint4*)Brow0;
    uint4 b1 = *(const uint4*)Brow1;
    *(uint4*)&lds[(size_t)t*8]            = a0;
    *(uint4*)&lds[(size_t)(t+256)*8]      = a1;
    *(uint4*)&lds[4096 + (size_t)t*8]     = b0;
    *(uint4*)&lds[4096 + (size_t)(t+256)*8] = b1;
  }
  __syncthreads();

  int cur = 0;
#pragma unroll 1
  for (int kt = 0; kt < 32; ++kt) {
    uint4 a0, a1, b0, b1;
    const bool pf = (kt < 31);
    if (pf) {                      // issue next-tile global loads early (latency hides under MFMA)
      int ko = (kt + 1) * 32;
      a0 = *(const uint4*)(Arow0 + ko);
      a1 = *(const uint4*)(Arow1 + ko);
      b0 = *(const uint4*)(Brow0 + ko);
      b1 = *(const uint4*)(Brow1 + ko);
    }
    const _Float16* la = lds + (size_t)cur * 8192;
    const _Float16* lb = la + 4096;
    f16x8 af[4], bf[4];
#pragma unroll
    for (int s = 0; s < 4; ++s) af[s] = *(const f16x8*)(la + aoff[s]);
#pragma unroll
    for (int s = 0; s < 4; ++s) bf[s] = *(const f16x8*)(lb + boff[s]);
#pragma unroll
    for (int i = 0; i < 4; ++i)
#pragma unroll
      for (int j = 0; j < 4; ++j)
        acc[i][j] = MFMA_F16(af[i], bf[j], acc[i][j]);
    if (pf) {
      _Float16* ld2 = lds + (size_t)(cur ^ 1) * 8192;
      *(uint4*)&ld2[(size_t)t*8]              = a0;
      *(uint4*)&ld2[(size_t)(t+256)*8]        = a1;
      *(uint4*)&ld2[4096 + (size_t)t*8]       = b0;
      *(uint4*)&ld2[4096 + (size_t)(t+256)*8] = b1;
      __syncthreads();
      cur ^= 1;
    }
  }
}

// ---------------- fused QKV projection (z=0:Q, 1:K, 2:V-transposed) ----------------
__global__ __launch_bounds__(256, 2) void k_qkv(const _Float16* __restrict__ dec16, const _Float16* __restrict__ enc16,
                                                const _Float16* __restrict__ wT,
                                                const float* __restrict__ bq, const float* __restrict__ bk,
                                                const float* __restrict__ bv,
                                                _Float16* __restrict__ Qo, _Float16* __restrict__ Ko,
                                                _Float16* __restrict__ Vt)
{
  __shared__ _Float16 lds[16384];
  const int z = blockIdx.z;
  const _Float16* A    = (z == 0) ? dec16 : enc16;
  const _Float16* BT   = wT + (size_t)z * (1024u*1024u);
  const float*    bias = (z == 0) ? bq : (z == 1) ? bk : bv;

  const int bx = blockIdx.x;             // 256 blocks: 32 m-tiles x 8 n-tiles
  const int m0 = (bx >> 3) * 128, n0 = (bx & 7) * 128;
  const int lane = threadIdx.x & 63, wid = threadIdx.x >> 6;
  const int lr = lane & 15, lg = lane >> 4;
  const int wm = (wid & 1) * 64, wn = (wid >> 1) * 64;

  f32x4 acc[4][4];
  gemm_core_128(A, BT, m0, n0, lds, acc);

  if (z < 2) {
    _Float16* dst = (z == 0) ? Qo : Ko;   // [b][h][s][64]
#pragma unroll
    for (int i = 0; i < 4; ++i)
#pragma unroll
      for (int j = 0; j < 4; ++j) {
        int n = n0 + wn + j*16 + lr;
        int h = n >> 6, d = n & 63;
        float bb = bias[n];
        f32x4 v = acc[i][j];
#pragma unroll
        for (int r = 0; r < 4; ++r) {
          int m = m0 + wm + i*16 + 4*lg + r;
          int b = m >> 11, s = m & 2047;
          dst[((size_t)(b*16 + h)*2048 + s)*64 + d] = (_Float16)(v[r] + bb);
        }
      }
  } else {
#pragma unroll
    for (int i = 0; i < 4; ++i)
#pragma unroll
      for (int j = 0; j < 4; ++j) {
        int n = n0 + wn + j*16 + lr;
        int h = n >> 6, d = n & 63;
        float bb = bias[n];
        int m = m0 + wm + i*16 + 4*lg;
        int b = m >> 11, s = m & 2047;
        f16x4 pv = {(_Float16)(acc[i][j][0] + bb), (_Float16)(acc[i][j][1] + bb),
                    (_Float16)(acc[i][j][2] + bb), (_Float16)(acc[i][j][3] + bb)};
        *(f16x4*)&Vt[((size_t)(b*16 + h)*64 + d)*2048 + s] = pv;   // [b][h][d][s]
      }
  }
}

// ---------------- output projection: d_out = ctx @ wo + bo (fp32 out) ----------------
__global__ __launch_bounds__(256, 2) void k_out(const _Float16* __restrict__ ctx, const _Float16* __restrict__ woT,
                                                const float* __restrict__ bo, float* __restrict__ out)
{
  __shared__ _Float16 lds[16384];
  const int bx = blockIdx.x;
  const int m0 = (bx >> 3) * 128, n0 = (bx & 7) * 128;
  const int lane = threadIdx.x & 63, wid = threadIdx.x >> 6;
  const int lr = lane & 15, lg = lane >> 4;
  const int wm = (wid & 1) * 64, wn = (wid >> 1) * 64;

  f32x4 acc[4][4];
  gemm_core_128(ctx, woT, m0, n0, lds, acc);

#pragma unroll
  for (int i = 0; i < 4; ++i)
#pragma unroll
    for (int j = 0; j < 4; ++j) {
      int n = n0 + wn + j*16 + lr;
      float bb = bo[n];
#pragma unroll
      for (int r = 0; r < 4; ++r) {
        int m = m0 + wm + i*16 + 4*lg + r;
        out[(size_t)m*1024 + n] = acc[i][j][r] + bb;
      }
    }
}

// ---------------- flash attention (no LDS; K/V L2-resident; swapped QK^T) ----------------
// Per wave: 32 q-rows. S^T = mfma(K,Q) so each S^T C-fragment IS a valid B-operand fragment
// for PV (k-index placement chosen identically on the V^T A-side -> correct for any HW k-perm).
__global__ __launch_bounds__(256, 2) void k_attn(const _Float16* __restrict__ Q, const _Float16* __restrict__ K,
                                                 const _Float16* __restrict__ Vt, _Float16* __restrict__ ctx)
{
  const int bid  = blockIdx.x;               // 512 blocks
  const int xcd  = bid & 7, slot = bid >> 3; // group 4 heads per XCD for L2 locality
  const int bh   = xcd*4 + (slot >> 4);
  const int qt   = slot & 15;
  const int wid  = threadIdx.x >> 6, lane = threadIdx.x & 63;
  const int lr   = lane & 15, lg = lane >> 4;
  const int qbase = qt*128 + wid*32;

  const _Float16* Qp = Q  + ((size_t)bh*2048 + qbase)*64;
  const _Float16* Kp = K  + (size_t)bh*2048*64;
  const _Float16* Vp = Vt + (size_t)bh*64*2048;

  const float ALPHA = 0.125f * 1.44269504f;  // scale * log2(e)
  const f32x4 z4 = {0.f,0.f,0.f,0.f};

  f16x8 qf[2][2];
#pragma unroll
  for (int qs = 0; qs < 2; ++qs)
#pragma unroll
    for (int d2 = 0; d2 < 2; ++d2)
      qf[qs][d2] = *(const f16x8*)&Qp[(size_t)(qs*16 + lr)*64 + d2*32 + 8*lg];

  f32x4 acc[4][2];
#pragma unroll
  for (int dt = 0; dt < 4; ++dt) { acc[dt][0] = z4; acc[dt][1] = z4; }
  float mrun[2] = {-3.0e38f, -3.0e38f};
  float lrun[2] = {0.f, 0.f};

#pragma unroll 1
  for (int kt = 0; kt < 64; ++kt) {
    const _Float16* kbp = Kp + (size_t)kt*32*64;
    f16x8 kf[2][2];
#pragma unroll
    for (int ks = 0; ks < 2; ++ks)
#pragma unroll
      for (int d2 = 0; d2 < 2; ++d2)
        kf[ks][d2] = *(const f16x8*)&kbp[(size_t)(ks*16 + lr)*64 + d2*32 + 8*lg];

    f16x8 vf[4];                              // V^T A-fragments: k = 4*lg+i (lo) / 16+4*lg+i (hi)
#pragma unroll
    for (int dt = 0; dt < 4; ++dt) {
      const _Float16* vr = Vp + (size_t)(dt*16 + lr)*2048 + kt*32 + 4*lg;
      union { f16x8 v8; f16x4 v4[2]; } u;
      u.v4[0] = *(const f16x4*)vr;
      u.v4[1] = *(const f16x4*)(vr + 16);
      vf[dt] = u.v8;
    }

    f32x4 st[2][2];                           // S^T[k][q]: [ksub][qsub]
#pragma unroll
    for (int ks = 0; ks < 2; ++ks)
#pragma unroll
      for (int qs = 0; qs < 2; ++qs) {
        f32x4 s = MFMA_F16(kf[ks][0], qf[qs][0], z4);
        st[ks][qs] = MFMA_F16(kf[ks][1], qf[qs][1], s);
      }

    f16x8 pt[2];
#pragma unroll
    for (int qs = 0; qs < 2; ++qs) {
      float pv[8];
#pragma unroll
      for (int i = 0; i < 4; ++i) { pv[i] = st[0][qs][i]; pv[4+i] = st[1][qs][i]; }
      float pm = pv[0];
#pragma unroll
      for (int i = 1; i < 8; ++i) pm = fmaxf(pm, pv[i]);
      pm = fmaxf(pm, __shfl_xor(pm, 16));
      pm = fmaxf(pm, __shfl_xor(pm, 32));
      float mn = fmaxf(mrun[qs], pm);
      float rr = exp2f((mrun[qs] - mn) * ALPHA);
      mrun[qs] = mn;
      float ssum = 0.f;
      f16x8 ptv;
#pragma unroll
      for (int i = 0; i < 8; ++i) {
        float e = exp2f((pv[i] - mn) * ALPHA);
        ssum += e;
        ptv[i] = (_Float16)e;
      }
      lrun[qs] = lrun[qs] * rr + ssum;
#pragma unroll
      for (int dt = 0; dt < 4; ++dt) acc[dt][qs] *= rr;
      pt[qs] = ptv;
    }

#pragma unroll
    for (int dt = 0; dt < 4; ++dt)
#pragma unroll
      for (int qs = 0; qs < 2; ++qs)
        acc[dt][qs] = MFMA_F16(vf[dt], pt[qs], acc[dt][qs]);
  }

#pragma unroll
  for (int qs = 0; qs < 2; ++qs) {
    float L = lrun[qs];
    L += __shfl_xor(L, 16);
    L += __shfl_xor(L, 32);
    float inv = 1.f / L;
    int q = qbase + qs*16 + lr;
    _Float16* cp = ctx + ((size_t)((bh >> 4)*2048 + q))*1024 + (bh & 15)*64;
#pragma unroll
    for (int dt = 0; dt < 4; ++dt) {
      f16x4 o = {(_Float16)(acc[dt][qs][0]*inv), (_Float16)(acc[dt][qs][1]*inv),
                 (_Float16)(acc[dt][qs][2]*inv), (_Float16)(acc[dt][qs][3]*inv)};
      *(f16x4*)&cp[dt*16 + 4*lg] = o;
    }
  }
}

// ---------------- launch ----------------
extern "C" void kernel_launch(void* const* d_in, const int* in_sizes, int n_in,
                              void* d_out, int out_size, void* d_ws, size_t ws_size,
                              hipStream_t stream) {
  const float* dec = (const float*)d_in[0];
  const float* enc = (const float*)d_in[1];
  const float* wq  = (const float*)d_in[2];
  const float* bq  = (const float*)d_in[3];
  const float* wk  = (const float*)d_in[4];
  const float* bk  = (const float*)d_in[5];
  const float* wv  = (const float*)d_in[6];
  const float* bv  = (const float*)d_in[7];
  const float* wo  = (const float*)d_in[8];
  const float* bo  = (const float*)d_in[9];

  char* ws = (char*)d_ws;
  _Float16* dec16 = (_Float16*)(ws + (0ull  << 20));
  _Float16* enc16 = (_Float16*)(ws + (8ull  << 20));
  _Float16* wT    = (_Float16*)(ws + (16ull << 20));
  _Float16* Qh    = (_Float16*)(ws + (24ull << 20));
  _Float16* Kh    = (_Float16*)(ws + (32ull << 20));
  _Float16* Vt    = (_Float16*)(ws + (40ull << 20));
  _Float16* ctx   = (_Float16*)(ws + (48ull << 20));
  float* out = (float*)d_out;

  k_cast<<<4096, 256, 0, stream>>>(dec, enc, dec16, enc16);
  k_wt<<<dim3(32, 32, 4), dim3(32, 8), 0, stream>>>(wq, wk, wv, wo, wT);
  k_qkv<<<dim3(256, 1, 3), 256, 0, stream>>>(dec16, enc16, wT, bq, bk, bv, Qh, Kh, Vt);
  k_attn<<<512, 256, 0, stream>>>(Qh, Kh, Vt, ctx);
  k_out<<<256, 256, 0, stream>>>(ctx, wT + 3ull*1024*1024, bo, out);
}

// Round 4
// 281.342 us; speedup vs baseline: 1.1803x; 1.1803x over previous
//
#include <hip/hip_runtime.h>
#include <hip/hip_fp16.h>

typedef __attribute__((ext_vector_type(8))) _Float16 f16x8;
typedef __attribute__((ext_vector_type(4))) _Float16 f16x4;
typedef __attribute__((ext_vector_type(4))) float    f32x4;

#define MFMA_F16(a,b,c) __builtin_amdgcn_mfma_f32_16x16x32_f16((a),(b),(c),0,0,0)

// ---------------- workspace layout (bytes) ----------------
// DEC16   @ 0        8 MB   [4096][1024] f16
// ENC16   @ 8 MB     8 MB
// WT      @ 16 MB    4x2 MB  wqT,wkT,wvT,woT  [n][k] f16
// QH      @ 24 MB    8 MB   [2][16][2048][64] f16
// KH      @ 32 MB    8 MB   [2][16][2048][64] f16
// VT      @ 40 MB    8 MB   [2][16][64][2048] f16 (k-permuted within 32-blocks)
// CTX     @ 48 MB    8 MB   [4096][1024] f16
// total 56 MB

// ---------------- cast activations fp32 -> fp16 ----------------
__global__ __launch_bounds__(256) void k_cast(const float* __restrict__ dec, const float* __restrict__ enc,
                                              _Float16* __restrict__ dd, _Float16* __restrict__ de)
{
  int i = blockIdx.x * 256 + threadIdx.x;          // 1048576 threads * float4 = 4194304 elems
  float4 a = ((const float4*)dec)[i];
  float4 b = ((const float4*)enc)[i];
  f16x4 ha = {(_Float16)a.x, (_Float16)a.y, (_Float16)a.z, (_Float16)a.w};
  f16x4 hb = {(_Float16)b.x, (_Float16)b.y, (_Float16)b.z, (_Float16)b.w};
  ((f16x4*)dd)[i] = ha;
  ((f16x4*)de)[i] = hb;
}

// ---------------- transpose+cast weights: wT[n][k] = (f16)w[k][n] ----------------
__global__ __launch_bounds__(256) void k_wt(const float* __restrict__ wq, const float* __restrict__ wk,
                                            const float* __restrict__ wv, const float* __restrict__ wo,
                                            _Float16* __restrict__ dst0)
{
  __shared__ float tile[32][33];
  int z = blockIdx.z;
  const float* w = (z==0)?wq:(z==1)?wk:(z==2)?wv:wo;
  _Float16* dst = dst0 + (size_t)z * (1024u*1024u);
  int tx = threadIdx.x, ty = threadIdx.y;          // block (32,8)
  int n0 = blockIdx.x*32, k0 = blockIdx.y*32;
#pragma unroll
  for (int r = 0; r < 4; ++r)
    tile[ty + 8*r][tx] = w[(size_t)(k0 + ty + 8*r)*1024 + n0 + tx];
  __syncthreads();
#pragma unroll
  for (int r = 0; r < 4; ++r)
    dst[(size_t)(n0 + ty + 8*r)*1024 + k0 + tx] = (_Float16)tile[tx][ty + 8*r];
}

// ---------------- shared 128x128x1024 GEMM core (B^T form, f16, reg-staged dbuf LDS) ----------------
// A: [M][1024] f16 row-major; BT: [1024][1024] f16 (row n = column n of W).
// acc[i][j] is the wave's 4x4 grid of 16x16 C tiles; C layout: col=lane&15, row=4*(lane>>4)+reg.
__device__ __forceinline__ void gemm_core_128(const _Float16* __restrict__ A, const _Float16* __restrict__ BT,
                                              int m0, int n0, _Float16* lds, f32x4 acc[4][4])
{
  const int t    = threadIdx.x;
  const int lane = t & 63, wid = t >> 6;
  const int lr   = lane & 15, lg = lane >> 4;
  const int wm   = (wid & 1) * 64, wn = (wid >> 1) * 64;
  const int swz  = (lr >> 2) & 3;

  // staging: thread t owns 16B chunks c=t and c=t+256 of each tile (chunk c -> row c>>2, slot c&3).
  // slot holds logical k-chunk (slot ^ ((row>>2)&3))  [XOR swizzle -> 2-way-free ds_read_b128 later]
  const int cm0 = t >> 2,        ck0 = (((t      ) & 3) ^ (((t      ) >> 4) & 3)) * 8;
  const int cm1 = (t + 256) >> 2, ck1 = (((t + 256) & 3) ^ (((t + 256) >> 4) & 3)) * 8;
  const _Float16* Arow0 = A  + (size_t)(m0 + cm0) * 1024 + ck0;
  const _Float16* Arow1 = A  + (size_t)(m0 + cm1) * 1024 + ck1;
  const _Float16* Brow0 = BT + (size_t)(n0 + cm0) * 1024 + ck0;
  const _Float16* Brow1 = BT + (size_t)(n0 + cm1) * 1024 + ck1;

  int aoff[4], boff[4];
#pragma unroll
  for (int s = 0; s < 4; ++s) {
    aoff[s] = (wm + s*16 + lr)*32 + ((lg ^ swz) << 3);
    boff[s] = (wn + s*16 + lr)*32 + ((lg ^ swz) << 3);
  }

  const f32x4 z4 = {0.f,0.f,0.f,0.f};
#pragma unroll
  for (int i = 0; i < 4; ++i)
#pragma unroll
    for (int j = 0; j < 4; ++j) acc[i][j] = z4;

  { // prologue: stage k-tile 0 into buf 0
    uint4 a0 = *(const uint4*)Arow0;
    uint4 a1 = *(const uint4*)Arow1;
    uint4 b0 = *(const uint4*)Brow0;
    uint4 b1 = *(const uint4*)Brow1;
    *(uint4*)&lds[(size_t)t*8]            = a0;
    *(uint4*)&lds[(size_t)(t+256)*8]      = a1;
    *(uint4*)&lds[4096 + (size_t)t*8]     = b0;
    *(uint4*)&lds[4096 + (size_t)(t+256)*8] = b1;
  }
  __syncthreads();

  int cur = 0;
#pragma unroll 1
  for (int kt = 0; kt < 32; ++kt) {
    uint4 a0, a1, b0, b1;
    const bool pf = (kt < 31);
    if (pf) {                      // issue next-tile global loads early (latency hides under MFMA)
      int ko = (kt + 1) * 32;
      a0 = *(const uint4*)(Arow0 + ko);
      a1 = *(const uint4*)(Arow1 + ko);
      b0 = *(const uint4*)(Brow0 + ko);
      b1 = *(const uint4*)(Brow1 + ko);
    }
    const _Float16* la = lds + (size_t)cur * 8192;
    const _Float16* lb = la + 4096;
    f16x8 af[4], bf[4];
#pragma unroll
    for (int s = 0; s < 4; ++s) af[s] = *(const f16x8*)(la + aoff[s]);
#pragma unroll
    for (int s = 0; s < 4; ++s) bf[s] = *(const f16x8*)(lb + boff[s]);
#pragma unroll
    for (int i = 0; i < 4; ++i)
#pragma unroll
      for (int j = 0; j < 4; ++j)
        acc[i][j] = MFMA_F16(af[i], bf[j], acc[i][j]);
    if (pf) {
      _Float16* ld2 = lds + (size_t)(cur ^ 1) * 8192;
      *(uint4*)&ld2[(size_t)t*8]              = a0;
      *(uint4*)&ld2[(size_t)(t+256)*8]        = a1;
      *(uint4*)&ld2[4096 + (size_t)t*8]       = b0;
      *(uint4*)&ld2[4096 + (size_t)(t+256)*8] = b1;
      __syncthreads();
      cur ^= 1;
    }
  }
}

// ---------------- fused QKV projection (z=0:Q, 1:K, 2:V-transposed-permuted) ----------------
__global__ __launch_bounds__(256, 2) void k_qkv(const _Float16* __restrict__ dec16, const _Float16* __restrict__ enc16,
                                                const _Float16* __restrict__ wT,
                                                const float* __restrict__ bq, const float* __restrict__ bk,
                                                const float* __restrict__ bv,
                                                _Float16* __restrict__ Qo, _Float16* __restrict__ Ko,
                                                _Float16* __restrict__ Vt)
{
  __shared__ _Float16 lds[16384];
  const int z = blockIdx.z;
  const _Float16* A    = (z == 0) ? dec16 : enc16;
  const _Float16* BT   = wT + (size_t)z * (1024u*1024u);
  const float*    bias = (z == 0) ? bq : (z == 1) ? bk : bv;

  const int bx = blockIdx.x;             // 256 blocks: 32 m-tiles x 8 n-tiles
  const int m0 = (bx >> 3) * 128, n0 = (bx & 7) * 128;
  const int lane = threadIdx.x & 63, wid = threadIdx.x >> 6;
  const int lr = lane & 15, lg = lane >> 4;
  const int wm = (wid & 1) * 64, wn = (wid >> 1) * 64;

  f32x4 acc[4][4];
  gemm_core_128(A, BT, m0, n0, lds, acc);

  if (z < 2) {
    _Float16* dst = (z == 0) ? Qo : Ko;   // [b][h][s][64]
#pragma unroll
    for (int i = 0; i < 4; ++i)
#pragma unroll
      for (int j = 0; j < 4; ++j) {
        int n = n0 + wn + j*16 + lr;
        int h = n >> 6, d = n & 63;
        float bb = bias[n];
        f32x4 v = acc[i][j];
#pragma unroll
        for (int r = 0; r < 4; ++r) {
          int m = m0 + wm + i*16 + 4*lg + r;
          int b = m >> 11, s = m & 2047;
          dst[((size_t)(b*16 + h)*2048 + s)*64 + d] = (_Float16)(v[r] + bb);
        }
      }
  } else {
#pragma unroll
    for (int i = 0; i < 4; ++i)
#pragma unroll
      for (int j = 0; j < 4; ++j) {
        int n = n0 + wn + j*16 + lr;
        int h = n >> 6, d = n & 63;
        float bb = bias[n];
        int m = m0 + wm + i*16 + 4*lg;
        int b = m >> 11, s = m & 2047;
        // k-permute within 32-block so attn lane's 8 V values are one 16B load:
        // pos(k) = 8*((k>>2)&3) + 4*((k>>4)&1) + (k&3)   (k&3==0 here, thread owns 4 consecutive)
        int sp = (s & ~31) | (((s >> 2) & 3) << 3) | (((s >> 4) & 1) << 2);
        f16x4 pv = {(_Float16)(acc[i][j][0] + bb), (_Float16)(acc[i][j][1] + bb),
                    (_Float16)(acc[i][j][2] + bb), (_Float16)(acc[i][j][3] + bb)};
        *(f16x4*)&Vt[((size_t)(b*16 + h)*64 + d)*2048 + sp] = pv;   // [b][h][d][s-perm]
      }
  }
}

// ---------------- output projection: d_out = ctx @ wo + bo (fp32 out) ----------------
__global__ __launch_bounds__(256, 2) void k_out(const _Float16* __restrict__ ctx, const _Float16* __restrict__ woT,
                                                const float* __restrict__ bo, float* __restrict__ out)
{
  __shared__ _Float16 lds[16384];
  const int bx = blockIdx.x;
  const int m0 = (bx >> 3) * 128, n0 = (bx & 7) * 128;
  const int lane = threadIdx.x & 63, wid = threadIdx.x >> 6;
  const int lr = lane & 15, lg = lane >> 4;
  const int wm = (wid & 1) * 64, wn = (wid >> 1) * 64;

  f32x4 acc[4][4];
  gemm_core_128(ctx, woT, m0, n0, lds, acc);

#pragma unroll
  for (int i = 0; i < 4; ++i)
#pragma unroll
    for (int j = 0; j < 4; ++j) {
      int n = n0 + wn + j*16 + lr;
      float bb = bo[n];
#pragma unroll
      for (int r = 0; r < 4; ++r) {
        int m = m0 + wm + i*16 + 4*lg + r;
        out[(size_t)m*1024 + n] = acc[i][j][r] + bb;
      }
    }
}

// ---------------- flash attention (no LDS; K/V L2-resident; swapped QK^T) ----------------
// Per wave: 32 q-rows. S^T = mfma(K,Q) so each S^T C-fragment IS a valid B-operand fragment
// for PV (k-index placement chosen identically on the V^T A-side -> correct for any HW k-perm).
// Register double-buffered K/V prefetch (named bufs A/B), defer-max, setprio around MFMA.
__global__ __launch_bounds__(256, 2) void k_attn(const _Float16* __restrict__ Q, const _Float16* __restrict__ K,
                                                 const _Float16* __restrict__ Vt, _Float16* __restrict__ ctx)
{
  const int bid  = blockIdx.x;               // 512 blocks
  const int xcd  = bid & 7, slot = bid >> 3; // group 4 heads per XCD for L2 locality
  const int bh   = xcd*4 + (slot >> 4);
  const int qt   = slot & 15;
  const int wid  = threadIdx.x >> 6, lane = threadIdx.x & 63;
  const int lr   = lane & 15, lg = lane >> 4;
  const int qbase = qt*128 + wid*32;

  const _Float16* Qp = Q  + ((size_t)bh*2048 + qbase)*64;
  const _Float16* Kp = K  + (size_t)bh*2048*64;
  const _Float16* Vp = Vt + (size_t)bh*64*2048;

  const float ALPHA = 0.125f * 1.44269504f;  // scale * log2(e)
  const float DTHR  = 6.0f;                  // defer-max threshold (pre-scale units): P <= 2^(6*ALPHA) ~ 2.1
  const f32x4 z4 = {0.f,0.f,0.f,0.f};

  f16x8 qf[2][2];
#pragma unroll
  for (int qs = 0; qs < 2; ++qs)
#pragma unroll
    for (int d2 = 0; d2 < 2; ++d2)
      qf[qs][d2] = *(const f16x8*)&Qp[(size_t)(qs*16 + lr)*64 + d2*32 + 8*lg];

  f32x4 acc[4][2];
#pragma unroll
  for (int dt = 0; dt < 4; ++dt) { acc[dt][0] = z4; acc[dt][1] = z4; }
  float mrun[2] = {-3.0e38f, -3.0e38f};
  float lrun[2] = {0.f, 0.f};

#define LOAD_KV(kf_, vf_, ktv_) {                                                        \
    const _Float16* kbp_ = Kp + (size_t)(ktv_)*32*64;                                    \
    _Pragma("unroll")                                                                    \
    for (int ks = 0; ks < 2; ++ks)                                                       \
      _Pragma("unroll")                                                                  \
      for (int d2 = 0; d2 < 2; ++d2)                                                     \
        kf_[ks][d2] = *(const f16x8*)&kbp_[(size_t)(ks*16 + lr)*64 + d2*32 + 8*lg];      \
    _Pragma("unroll")                                                                    \
    for (int dt = 0; dt < 4; ++dt)                                                       \
      vf_[dt] = *(const f16x8*)&Vp[(size_t)(dt*16 + lr)*2048 + (ktv_)*32 + 8*lg];        \
  }

#define ATTN_STEP(kf_, vf_) {                                                            \
    f32x4 st[2][2];                                                                      \
    __builtin_amdgcn_s_setprio(1);                                                       \
    _Pragma("unroll")                                                                    \
    for (int ks = 0; ks < 2; ++ks)                                                       \
      _Pragma("unroll")                                                                  \
      for (int qs = 0; qs < 2; ++qs) {                                                   \
        f32x4 s_ = MFMA_F16(kf_[ks][0], qf[qs][0], z4);                                  \
        st[ks][qs] = MFMA_F16(kf_[ks][1], qf[qs][1], s_);                                \
      }                                                                                  \
    __builtin_amdgcn_s_setprio(0);                                                       \
    f16x8 pt[2];                                                                         \
    _Pragma("unroll")                                                                    \
    for (int qs = 0; qs < 2; ++qs) {                                                     \
      float pv[8];                                                                       \
      _Pragma("unroll")                                                                  \
      for (int i = 0; i < 4; ++i) { pv[i] = st[0][qs][i]; pv[4+i] = st[1][qs][i]; }      \
      float pm = fmaxf(fmaxf(fmaxf(pv[0], pv[1]), fmaxf(pv[2], pv[3])),                  \
                       fmaxf(fmaxf(pv[4], pv[5]), fmaxf(pv[6], pv[7])));                 \
      pm = fmaxf(pm, __shfl_xor(pm, 16));                                                \
      pm = fmaxf(pm, __shfl_xor(pm, 32));                                                \
      float mn = mrun[qs];                                                               \
      if (!__all(pm <= mn + DTHR)) {                                                     \
        mn = fmaxf(mn, pm);                                                              \
        float rr = exp2f((mrun[qs] - mn) * ALPHA);                                       \
        mrun[qs] = mn;                                                                   \
        lrun[qs] *= rr;                                                                  \
        _Pragma("unroll")                                                                \
        for (int dt = 0; dt < 4; ++dt) acc[dt][qs] *= rr;                                \
      }                                                                                  \
      float ssum = 0.f;                                                                  \
      f16x8 ptv;                                                                         \
      _Pragma("unroll")                                                                  \
      for (int i = 0; i < 8; ++i) {                                                      \
        float e = exp2f((pv[i] - mn) * ALPHA);                                           \
        ssum += e;                                                                       \
        ptv[i] = (_Float16)e;                                                            \
      }                                                                                  \
      lrun[qs] += ssum;                                                                  \
      pt[qs] = ptv;                                                                      \
    }                                                                                    \
    __builtin_amdgcn_s_setprio(1);                                                       \
    _Pragma("unroll")                                                                    \
    for (int dt = 0; dt < 4; ++dt)                                                       \
      _Pragma("unroll")                                                                  \
      for (int qs = 0; qs < 2; ++qs)                                                     \
        acc[dt][qs] = MFMA_F16(vf_[dt], pt[qs], acc[dt][qs]);                            \
    __builtin_amdgcn_s_setprio(0);                                                       \
  }

  f16x8 kfA[2][2], vfA[4], kfB[2][2], vfB[4];
  LOAD_KV(kfA, vfA, 0);

#pragma unroll 1
  for (int kt = 0; kt < 64; kt += 2) {
    LOAD_KV(kfB, vfB, kt + 1);       // prefetch odd tile; latency hides under even-tile compute
    ATTN_STEP(kfA, vfA);
    int ktn = (kt + 2) & 63;         // 64 wraps to 0 (harmless dummy prefetch on last iter)
    LOAD_KV(kfA, vfA, ktn);          // prefetch next even tile under odd-tile compute
    ATTN_STEP(kfB, vfB);
  }

#pragma unroll
  for (int qs = 0; qs < 2; ++qs) {
    float L = lrun[qs];
    L += __shfl_xor(L, 16);
    L += __shfl_xor(L, 32);
    float inv = 1.f / L;
    int q = qbase + qs*16 + lr;
    _Float16* cp = ctx + ((size_t)((bh >> 4)*2048 + q))*1024 + (bh & 15)*64;
#pragma unroll
    for (int dt = 0; dt < 4; ++dt) {
      f16x4 o = {(_Float16)(acc[dt][qs][0]*inv), (_Float16)(acc[dt][qs][1]*inv),
                 (_Float16)(acc[dt][qs][2]*inv), (_Float16)(acc[dt][qs][3]*inv)};
      *(f16x4*)&cp[dt*16 + 4*lg] = o;
    }
  }
#undef LOAD_KV
#undef ATTN_STEP
}

// ---------------- launch ----------------
extern "C" void kernel_launch(void* const* d_in, const int* in_sizes, int n_in,
                              void* d_out, int out_size, void* d_ws, size_t ws_size,
                              hipStream_t stream) {
  const float* dec = (const float*)d_in[0];
  const float* enc = (const float*)d_in[1];
  const float* wq  = (const float*)d_in[2];
  const float* bq  = (const float*)d_in[3];
  const float* wk  = (const float*)d_in[4];
  const float* bk  = (const float*)d_in[5];
  const float* wv  = (const float*)d_in[6];
  const float* bv  = (const float*)d_in[7];
  const float* wo  = (const float*)d_in[8];
  const float* bo  = (const float*)d_in[9];

  char* ws = (char*)d_ws;
  _Float16* dec16 = (_Float16*)(ws + (0ull  << 20));
  _Float16* enc16 = (_Float16*)(ws + (8ull  << 20));
  _Float16* wT    = (_Float16*)(ws + (16ull << 20));
  _Float16* Qh    = (_Float16*)(ws + (24ull << 20));
  _Float16* Kh    = (_Float16*)(ws + (32ull << 20));
  _Float16* Vt    = (_Float16*)(ws + (40ull << 20));
  _Float16* ctx   = (_Float16*)(ws + (48ull << 20));
  float* out = (float*)d_out;

  k_cast<<<4096, 256, 0, stream>>>(dec, enc, dec16, enc16);
  k_wt<<<dim3(32, 32, 4), dim3(32, 8), 0, stream>>>(wq, wk, wv, wo, wT);
  k_qkv<<<dim3(256, 1, 3), 256, 0, stream>>>(dec16, enc16, wT, bq, bk, bv, Qh, Kh, Vt);
  k_attn<<<512, 256, 0, stream>>>(Qh, Kh, Vt, ctx);
  k_out<<<256, 256, 0, stream>>>(ctx, wT + 3ull*1024*1024, bo, out);
}